// Round 2
// baseline (348.123 us; speedup 1.0000x reference)
//
#include <hip/hip_runtime.h>

#define CH 128
#define NCLS 16
#define CHK 16          // channels per chunk
#define NCHUNK 8        // 8 chunks of 16 == 128 channels, one per XCD
#define ECAP 131072     // bucket capacity per partition (E/8 = 100k expected)
#define NODECAP 64      // fixed esrc slots per node (max deg+1 ~ 36 expected)

typedef __attribute__((ext_vector_type(8))) short bf16x8;
typedef __attribute__((ext_vector_type(4))) float f32x4;
typedef __attribute__((ext_vector_type(4))) unsigned u32x4;

__device__ inline ushort f2bf(float f) {        // RTNE fp32 -> bf16 bits
    unsigned u = __float_as_uint(f);
    unsigned r = u + 0x7fffu + ((u >> 16) & 1u);
    return (ushort)(r >> 16);
}
__device__ inline float bf2f(ushort b) {
    return __uint_as_float(((unsigned)b) << 16);
}

// ---------------------------------------------------------------- prep (fused)
// b<128: bf16 hi/lo weight split. Next nbi blocks: init the fixed-stride CSR --
// every node region pre-filled with pad (node n => zero row), self-edge at
// slot 0, cursor=1. Last block: zero bufA row n per chunk + pcnt.
__global__ __launch_bounds__(256) void prep_kernel(
    const float* __restrict__ W1, const float* __restrict__ W2,
    ushort* __restrict__ w1hi, ushort* __restrict__ w1lo,
    ushort* __restrict__ w2hi, ushort* __restrict__ w2lo,
    int* __restrict__ cursor, int* __restrict__ pcnt,
    ushort* __restrict__ esrc, float* __restrict__ bufA, int n, int nbi) {
    int b = blockIdx.x, tid = threadIdx.x;
    if (b < 128) {
        const float* W = (b < 64) ? W1 : W2;
        ushort* Whi = (b < 64) ? w1hi : w2hi;
        ushort* Wlo = (b < 64) ? w1lo : w2lo;
        int t = ((b & 63) << 8) + tid;
        int k = t >> 7, nn = t & 127;
        float v = W[t];
        ushort h = f2bf(v);
        Whi[nn * CH + k] = h;
        Wlo[nn * CH + k] = f2bf(v - bf2f(h));
    } else if (b < 128 + nbi) {
        // 32 nodes/block; 8 threads/node write the full 128B region (coalesced)
        int nb0 = (b - 128) * 32;
        int node = nb0 + (tid >> 3);
        if (node < n) {
            short pad = (short)(ushort)n;
            bf16x8 v = {pad, pad, pad, pad, pad, pad, pad, pad};
            if ((tid & 7) == 0) v[0] = (short)(ushort)node;   // self-loop
            *(bf16x8*)&esrc[((size_t)node << 6) + (size_t)(tid & 7) * 8] = v;
        }
        if (tid < 32 && nb0 + tid < n) cursor[nb0 + tid] = 1;
    } else {
        if (tid < NCHUNK * CHK) {
            int c = tid >> 4, ch = tid & 15;
            bufA[((size_t)c * (n + 1) + n) * CHK + ch] = 0.0f;
        }
        if (tid < 8) pcnt[tid] = 0;
    }
}

// ---------------------------------------------------------------- bucket pass
// One pass over edges: pack (dst<<16)|src into 8 dst-partition buckets.
// Block-level LDS aggregation => 8 global atomics per block (no hot counters).
__global__ __launch_bounds__(256) void bucket_kernel(
    const int* __restrict__ src, const int* __restrict__ dst,
    unsigned* __restrict__ ebuf, int* __restrict__ pcnt, int E, float p8n) {
    __shared__ int lpos[8];
    __shared__ int lbase[8];
    int tid = threadIdx.x;
    if (tid < 8) lpos[tid] = 0;
    __syncthreads();
    int i0 = (blockIdx.x * 256 + tid) * 4;
    int part[4]; int off[4]; unsigned pk[4]; int cnt = 0;
    if (i0 + 3 < E) {
        int4 s4 = *(const int4*)&src[i0];
        int4 d4 = *(const int4*)&dst[i0];
        int ss[4] = {s4.x, s4.y, s4.z, s4.w};
        int dd[4] = {d4.x, d4.y, d4.z, d4.w};
        cnt = 4;
#pragma unroll
        for (int k = 0; k < 4; k++) {
            part[k] = min(7, (int)((float)dd[k] * p8n));
            pk[k] = ((unsigned)dd[k] << 16) | (unsigned)ss[k];
            off[k] = atomicAdd(&lpos[part[k]], 1);
        }
    } else {
        for (int k = 0; k < 4 && i0 + k < E; k++) {
            int s = src[i0 + k], d = dst[i0 + k];
            part[cnt] = min(7, (int)((float)d * p8n));
            pk[cnt] = ((unsigned)d << 16) | (unsigned)s;
            off[cnt] = atomicAdd(&lpos[part[cnt]], 1);
            cnt++;
        }
    }
    __syncthreads();
    if (tid < 8) lbase[tid] = atomicAdd(&pcnt[tid], lpos[tid]);
    __syncthreads();
    for (int k = 0; k < cnt; k++) {
        int idx = lbase[part[k]] + off[k];
        if (idx < ECAP) ebuf[(size_t)part[k] * ECAP + idx] = pk[k];
    }
}

// ---------------------------------------------------------------- CSR fill
// XCD-partitioned; each partition reads ONLY its own bucket (0.4MB, not the
// full 6.4MB edge list). grid = 8 partitions x 256 blocks.
__global__ __launch_bounds__(256) void fill_kernel(
    const unsigned* __restrict__ ebuf, const int* __restrict__ pcnt,
    int* __restrict__ cursor, ushort* __restrict__ esrc) {
    int part = blockIdx.x & 7;
    int m = min(pcnt[part], ECAP);
    const unsigned* bk = ebuf + (size_t)part * ECAP;
    int stride = (int)(gridDim.x >> 3) * 256;
    for (int e = (int)(blockIdx.x >> 3) * 256 + threadIdx.x; e < m; e += stride) {
        unsigned pe = bk[e];
        int d = pe >> 16;
        int s = pe & 0xffff;
        int p = atomicAdd(&cursor[d], 1);
        if (p < NODECAP) esrc[((size_t)d << 6) + p] = (ushort)s;
    }
}

// ---------------------------------------------------------------- finalize
// cursor => degree => dis + padded count. Pads already pre-written by prep.
__global__ __launch_bounds__(256) void fin_kernel(
    const int* __restrict__ cursor, int* __restrict__ rsp,
    float* __restrict__ dis, int n) {
    int i = blockIdx.x * 256 + threadIdx.x;
    if (i >= n) return;
    int deg = cursor[i] - 1;
    dis[i] = rsqrtf((float)deg + 1.0f);
    rsp[i] = (deg + 8) & ~7;          // round8(deg+1), <= NODECAP
}

// ---------------------------------------------------------------- MFMA GEMM v3
// C = relu?(A) @ W, bf16 hi/lo split. Wave = 64 rows x 4 N-tiles: per k0,
// 4 A-frags (hi/lo) loaded once, each B hi/lo pair feeds 12 MFMAs.
// C chunk-major with pitch (n_rows+1), rows PRE-SCALED by dis[row].
template <bool RELU_IN>
__global__ __launch_bounds__(256, 2) void gemm_mfma(
    const float* __restrict__ A, const ushort* __restrict__ Bthi,
    const ushort* __restrict__ Btlo, const float* __restrict__ dis,
    float* __restrict__ C, int n_rows) {
    const int tid = threadIdx.x;
    const int bm0 = blockIdx.x * 256;        // block covers 256 rows
    const int wv = tid >> 6;
    const int lane = tid & 63;
    const int col = lane & 15;     // A row-in-frag / B col / C col
    const int quad = lane >> 4;    // k-block for A/B; row-quad for C
    const int rbase = bm0 + wv * 64 + col;   // wave rows: rbase + m*16
    const int ntBase = blockIdx.y * 4;

    f32x4 acc[4][4];   // [m][nt]
#pragma unroll
    for (int m = 0; m < 4; m++)
#pragma unroll
        for (int t = 0; t < 4; t++) acc[m][t] = (f32x4){0.f, 0.f, 0.f, 0.f};

#pragma unroll
    for (int k0 = 0; k0 < 4; k0++) {
        const int kb = k0 * 32 + quad * 8;
        bf16x8 ah[4], al[4];
#pragma unroll
        for (int m = 0; m < 4; m++) {
            int arow = rbase + m * 16;
            bool av = (arow < n_rows);
            const float* __restrict__ Ap = A + (size_t)arow * CH + kb;
            float4 f0 = av ? *(const float4*)Ap       : make_float4(0.f, 0.f, 0.f, 0.f);
            float4 f1 = av ? *(const float4*)(Ap + 4) : make_float4(0.f, 0.f, 0.f, 0.f);
            if (RELU_IN) {
                f0.x = fmaxf(f0.x, 0.f); f0.y = fmaxf(f0.y, 0.f);
                f0.z = fmaxf(f0.z, 0.f); f0.w = fmaxf(f0.w, 0.f);
                f1.x = fmaxf(f1.x, 0.f); f1.y = fmaxf(f1.y, 0.f);
                f1.z = fmaxf(f1.z, 0.f); f1.w = fmaxf(f1.w, 0.f);
            }
            float fa[8] = {f0.x, f0.y, f0.z, f0.w, f1.x, f1.y, f1.z, f1.w};
#pragma unroll
            for (int j = 0; j < 8; j++) {
                ushort h = f2bf(fa[j]);
                ah[m][j] = (short)h;
                al[m][j] = (short)f2bf(fa[j] - bf2f(h));
            }
        }
#pragma unroll
        for (int t = 0; t < 4; t++) {
            const int boff = ((ntBase + t) * 16 + col) * CH + kb;
            bf16x8 bh = *(const bf16x8*)&Bthi[boff];
            bf16x8 bl = *(const bf16x8*)&Btlo[boff];
#pragma unroll
            for (int m = 0; m < 4; m++) {
                acc[m][t] = __builtin_amdgcn_mfma_f32_16x16x32_bf16(ah[m], bh, acc[m][t], 0, 0, 0);
                acc[m][t] = __builtin_amdgcn_mfma_f32_16x16x32_bf16(ah[m], bl, acc[m][t], 0, 0, 0);
                acc[m][t] = __builtin_amdgcn_mfma_f32_16x16x32_bf16(al[m], bh, acc[m][t], 0, 0, 0);
            }
        }
    }

    // epilogue: C/D layout col=lane&15, row=quad*4+reg (m89-verified)
#pragma unroll
    for (int m = 0; m < 4; m++) {
#pragma unroll
        for (int reg = 0; reg < 4; reg++) {
            int gr = bm0 + wv * 64 + m * 16 + quad * 4 + reg;
            if (gr < n_rows) {
                float d = dis[gr];
#pragma unroll
                for (int t = 0; t < 4; t++) {
                    int nt = ntBase + t;
                    C[((size_t)nt * (n_rows + 1) + gr) * CHK + col] = acc[m][t][reg] * d;
                }
            }
        }
    }
}

// ---------------------------------------------------------------- CSR gather
// wave = (16 nodes, 1 chunk); chunk = blockIdx%8 pins the 3.2MB slice/XCD.
// (a) each block linearly pre-warms its share of the chunk slice -- converts
// the random-order first-touch into sequential fetch; (b) out-stores are
// NON-TEMPORAL; (c) NEW: esrc edge-list loads are NON-TEMPORAL -- the 6.4MB
// per-XCD esrc stream was evicting the 3.2MB L2-resident slice (6.4+3.2 >>
// 4MB L2), turning the random hC reads into L3/HBM misses. nt keeps the
// slice resident. Node i's edges live at [i*64, i*64+rsp[i]).
__global__ __launch_bounds__(256) void gather_kernel(
    const int* __restrict__ rsp, const ushort* __restrict__ esrc,
    const float* __restrict__ dis, const float* __restrict__ hC,
    const float* __restrict__ bias, float* __restrict__ out, int n) {
    int c = blockIdx.x & 7;
    int wv = threadIdx.x >> 6;
    int lane = threadIdx.x & 63;
    int g = lane >> 2;    // node slot 0..15
    int q = lane & 3;     // float4 within the 16-channel row
    int i = (blockIdx.x >> 3) * 64 + wv * 16 + g;
    bool valid = (i < n);
    int iw = valid ? i : 0;
    const float4* __restrict__ h4 = (const float4*)(hC + (size_t)c * (n + 1) * CHK);

    // sequential L2 pre-warm: one float4 per thread covers the slice
    float warm = 0.f;
    {
        int nblk = (n + 63) >> 6;                       // blocks per chunk
        size_t p = (size_t)(blockIdx.x >> 3) * 256 + threadIdx.x;
        size_t sliceF4 = ((size_t)(n + 1) * CHK) >> 2;  // float4 count
        for (; p < sliceF4; p += (size_t)nblk * 256) {
            float4 v = h4[p];
            warm += v.x + v.y + v.z + v.w;
        }
    }

    int beg = iw << 6;
    int pc = valid ? rsp[iw] : 0;     // padded count, multiple of 8, <= 64
    float4 acc = make_float4(0.f, 0.f, 0.f, 0.f);
    for (int j = beg; j < beg + pc; j += 8) {
        u32x4 ee = __builtin_nontemporal_load((const u32x4*)&esrc[j]);
        float4 v0 = h4[(size_t)(ee.x & 0xffffu) * 4 + q];
        float4 v1 = h4[(size_t)(ee.x >> 16) * 4 + q];
        float4 v2 = h4[(size_t)(ee.y & 0xffffu) * 4 + q];
        float4 v3 = h4[(size_t)(ee.y >> 16) * 4 + q];
        float4 v4 = h4[(size_t)(ee.z & 0xffffu) * 4 + q];
        float4 v5 = h4[(size_t)(ee.z >> 16) * 4 + q];
        float4 v6 = h4[(size_t)(ee.w & 0xffffu) * 4 + q];
        float4 v7 = h4[(size_t)(ee.w >> 16) * 4 + q];
        acc.x += v0.x; acc.y += v0.y; acc.z += v0.z; acc.w += v0.w;
        acc.x += v1.x; acc.y += v1.y; acc.z += v1.z; acc.w += v1.w;
        acc.x += v2.x; acc.y += v2.y; acc.z += v2.z; acc.w += v2.w;
        acc.x += v3.x; acc.y += v3.y; acc.z += v3.z; acc.w += v3.w;
        acc.x += v4.x; acc.y += v4.y; acc.z += v4.z; acc.w += v4.w;
        acc.x += v5.x; acc.y += v5.y; acc.z += v5.z; acc.w += v5.w;
        acc.x += v6.x; acc.y += v6.y; acc.z += v6.z; acc.w += v6.w;
        acc.x += v7.x; acc.y += v7.y; acc.z += v7.z; acc.w += v7.w;
    }
    // keep the warm loads alive (cannot be DCE'd)
    __asm__ volatile("" : : "v"(warm));
    if (valid) {
        float di = dis[iw];
        float4 bv = ((const float4*)bias)[c * 4 + q];
        f32x4 o;
        o[0] = bv.x + di * acc.x;
        o[1] = bv.y + di * acc.y;
        o[2] = bv.z + di * acc.z;
        o[3] = bv.w + di * acc.w;
        __builtin_nontemporal_store(o, (f32x4*)&((float4*)out)[(size_t)iw * 32 + c * 4 + q]);
    }
}

// ---------------------------------------------------------------- head
__global__ __launch_bounds__(256) void head_kernel(
    const float* __restrict__ A, const float* __restrict__ Wh,
    const float* __restrict__ bh, float* __restrict__ out, int n) {
    __shared__ float Ws[CH * NCLS];
    __shared__ float As[16][129];
    const int tid = threadIdx.x;
    const int n0 = blockIdx.x * 16;
#pragma unroll
    for (int i = 0; i < 8; i++) {
        int l = tid + i * 256;
        Ws[l] = Wh[l];
    }
#pragma unroll
    for (int i = 0; i < 8; i++) {
        int l = tid + i * 256;
        int r = l >> 7, c = l & 127;
        int gr = n0 + r;
        As[r][c] = (gr < n) ? fmaxf(A[(size_t)gr * CH + c], 0.0f) : 0.0f;
    }
    __syncthreads();
    int r = tid >> 4, c = tid & 15;
    float acc = bh[c];
#pragma unroll
    for (int k = 0; k < CH; k++) acc = fmaf(As[r][k], Ws[k * NCLS + c], acc);
    int gr = n0 + r;
    if (gr < n) out[(size_t)gr * NCLS + c] = acc;
}

// ---------------------------------------------------------------- launch
extern "C" void kernel_launch(void* const* d_in, const int* in_sizes, int n_in,
                              void* d_out, int out_size, void* d_ws, size_t ws_size,
                              hipStream_t stream) {
    const float* x  = (const float*)d_in[0];
    const int*   ei = (const int*)d_in[1];
    const float* W1 = (const float*)d_in[2];
    const float* b1 = (const float*)d_in[3];
    const float* W2 = (const float*)d_in[4];
    const float* b2 = (const float*)d_in[5];
    const float* Wh = (const float*)d_in[6];
    const float* bh = (const float*)d_in[7];
    float* out = (float*)d_out;

    const int n = in_sizes[0] / CH;   // 50000
    const int E = in_sizes[1] / 2;    // 800000
    const int* src = ei;
    const int* dst = ei + E;

    // workspace layout (all chunks 16B aligned)
    ushort* w1hi = (ushort*)d_ws;                    // 16384 each
    ushort* w1lo = w1hi + CH * CH;
    ushort* w2hi = w1lo + CH * CH;
    ushort* w2lo = w2hi + CH * CH;
    float* dis  = (float*)(w2lo + CH * CH);          // n
    float* bufA = dis + n;                           // (n+1)*128 chunk-major h'
    float* bufB = bufA + (size_t)(n + 1) * CH;       // n*128 row-major
    int* rsp    = (int*)(bufB + (size_t)n * CH);     // n (padded counts)
    int* cursor = rsp + n;                           // n
    int* pcnt   = cursor + n;                        // 8
    ushort* esrc = (ushort*)(pcnt + 8);              // n*64 fixed-stride CSR
    unsigned* ebuf = (unsigned*)bufB;                // 8*ECAP, aliases bufB
                                                     // (dead until gather1)

    const int B = 256;
    const int nbi = (n + 31) / 32;                   // esrc/cursor init blocks
    const float p8n = 8.0f / (float)n;               // partition map scale

    // ---- prep + bucketed fixed-stride CSR build (no count, no scans)
    prep_kernel<<<128 + nbi + 1, B, 0, stream>>>(W1, W2, w1hi, w1lo, w2hi, w2lo,
                                                 cursor, pcnt, esrc, bufA, n, nbi);
    bucket_kernel<<<(E + 1023) / 1024, B, 0, stream>>>(src, dst, ebuf, pcnt, E, p8n);
    fill_kernel<<<2048, B, 0, stream>>>(ebuf, pcnt, cursor, esrc);
    fin_kernel<<<(n + 255) / 256, B, 0, stream>>>(cursor, rsp, dis, n);

    const dim3 gemmGrid((n + 255) / 256, 2);
    const int gatherGrid = NCHUNK * ((n + 63) / 64);   // 64 nodes/block/chunk

    // layer 1
    gemm_mfma<false><<<gemmGrid, B, 0, stream>>>(x, w1hi, w1lo, dis, bufA, n);
    gather_kernel<<<gatherGrid, B, 0, stream>>>(rsp, esrc, dis, bufA, b1, bufB, n);
    // layer 2
    gemm_mfma<true><<<gemmGrid, B, 0, stream>>>(bufB, w2hi, w2lo, dis, bufA, n);
    gather_kernel<<<gatherGrid, B, 0, stream>>>(rsp, esrc, dis, bufA, b2, bufB, n);
    // head
    head_kernel<<<(n + 15) / 16, B, 0, stream>>>(bufB, Wh, bh, out, n);
}

// Round 3
// 321.508 us; speedup vs baseline: 1.0828x; 1.0828x over previous
//
#include <hip/hip_runtime.h>

#define CH 128
#define NCLS 16
#define CHK 16          // channels per chunk
#define NCHUNK 8        // 8 chunks of 16 == 128 channels, one per XCD
#define ECAP 131072     // bucket capacity per partition (E/8 = 100k expected)
#define SCAN_IPB 1024   // items per block in scan pass 1

typedef __attribute__((ext_vector_type(8))) short bf16x8;
typedef __attribute__((ext_vector_type(4))) float f32x4;

__device__ inline ushort f2bf(float f) {        // RTNE fp32 -> bf16 bits
    unsigned u = __float_as_uint(f);
    unsigned r = u + 0x7fffu + ((u >> 16) & 1u);
    return (ushort)(r >> 16);
}
__device__ inline float bf2f(ushort b) {
    return __uint_as_float(((unsigned)b) << 16);
}

// ---------------------------------------------------------------- prep (fused)
// b<128: bf16 hi/lo weight split. Next nbz blocks: zero cnt. Last block:
// zero bufA row n per chunk + pcnt.
__global__ __launch_bounds__(256) void prep_kernel(
    const float* __restrict__ W1, const float* __restrict__ W2,
    ushort* __restrict__ w1hi, ushort* __restrict__ w1lo,
    ushort* __restrict__ w2hi, ushort* __restrict__ w2lo,
    int* __restrict__ cnt, int* __restrict__ pcnt,
    float* __restrict__ bufA, int n, int nbz) {
    int b = blockIdx.x, tid = threadIdx.x;
    if (b < 128) {
        const float* W = (b < 64) ? W1 : W2;
        ushort* Whi = (b < 64) ? w1hi : w2hi;
        ushort* Wlo = (b < 64) ? w1lo : w2lo;
        int t = ((b & 63) << 8) + tid;
        int k = t >> 7, nn = t & 127;
        float v = W[t];
        ushort h = f2bf(v);
        Whi[nn * CH + k] = h;
        Wlo[nn * CH + k] = f2bf(v - bf2f(h));
    } else if (b < 128 + nbz) {
        int i = (b - 128) * 256 + tid;
        if (i < n) cnt[i] = 0;
    } else {
        if (tid < NCHUNK * CHK) {
            int c = tid >> 4, ch = tid & 15;
            bufA[((size_t)c * (n + 1) + n) * CHK + ch] = 0.0f;
        }
        if (tid < 8) pcnt[tid] = 0;
    }
}

// ---------------------------------------------------------------- bucket pass
// One pass over edges: pack (dst<<16)|src into 8 dst-partition buckets.
// Block-level LDS aggregation => 8 global atomics per block (no hot counters).
__global__ __launch_bounds__(256) void bucket_kernel(
    const int* __restrict__ src, const int* __restrict__ dst,
    unsigned* __restrict__ ebuf, int* __restrict__ pcnt, int E, float p8n) {
    __shared__ int lpos[8];
    __shared__ int lbase[8];
    int tid = threadIdx.x;
    if (tid < 8) lpos[tid] = 0;
    __syncthreads();
    int i0 = (blockIdx.x * 256 + tid) * 4;
    int part[4]; int off[4]; unsigned pk[4]; int cnt = 0;
    if (i0 + 3 < E) {
        int4 s4 = *(const int4*)&src[i0];
        int4 d4 = *(const int4*)&dst[i0];
        int ss[4] = {s4.x, s4.y, s4.z, s4.w};
        int dd[4] = {d4.x, d4.y, d4.z, d4.w};
        cnt = 4;
#pragma unroll
        for (int k = 0; k < 4; k++) {
            part[k] = min(7, (int)((float)dd[k] * p8n));
            pk[k] = ((unsigned)dd[k] << 16) | (unsigned)ss[k];
            off[k] = atomicAdd(&lpos[part[k]], 1);
        }
    } else {
        for (int k = 0; k < 4 && i0 + k < E; k++) {
            int s = src[i0 + k], d = dst[i0 + k];
            part[cnt] = min(7, (int)((float)d * p8n));
            pk[cnt] = ((unsigned)d << 16) | (unsigned)s;
            off[cnt] = atomicAdd(&lpos[part[cnt]], 1);
            cnt++;
        }
    }
    __syncthreads();
    if (tid < 8) lbase[tid] = atomicAdd(&pcnt[tid], lpos[tid]);
    __syncthreads();
    for (int k = 0; k < cnt; k++) {
        int idx = lbase[part[k]] + off[k];
        if (idx < ECAP) ebuf[(size_t)part[k] * ECAP + idx] = pk[k];
    }
}

// ---------------------------------------------------------------- degree count
// Partition-local: each partition reads ONLY its own 0.4MB bucket; atomics
// land on the partition's 25KB cnt slice (L2-resident on its XCD).
__global__ __launch_bounds__(256) void count_kernel(
    const unsigned* __restrict__ ebuf, const int* __restrict__ pcnt,
    int* __restrict__ cnt) {
    int part = blockIdx.x & 7;
    int m = min(pcnt[part], ECAP);
    const unsigned* bk = ebuf + (size_t)part * ECAP;
    int stride = (int)(gridDim.x >> 3) * 256;
    for (int e = (int)(blockIdx.x >> 3) * 256 + threadIdx.x; e < m; e += stride) {
        atomicAdd(&cnt[bk[e] >> 16], 1);
    }
}

// ---------------------------------------------------------------- scan (CSR)
__global__ __launch_bounds__(256) void scan1_kernel(
    const int* __restrict__ cnt, int* __restrict__ rsp,
    int* __restrict__ bsum, float* __restrict__ dis, int n) {
    __shared__ int lds[256];
    int t = threadIdx.x, b = blockIdx.x;
    int base = b * SCAN_IPB + t * 4;
    int v[4];
    int s = 0;
#pragma unroll
    for (int k = 0; k < 4; k++) {
        if (base + k < n) {
            int c = cnt[base + k];
            v[k] = (c + 8) & ~7;        // round8(c+1)
            dis[base + k] = rsqrtf((float)c + 1.0f);
        } else v[k] = 0;
        s += v[k];
    }
    lds[t] = s;
    __syncthreads();
    for (int off = 1; off < 256; off <<= 1) {
        int x = (t >= off) ? lds[t - off] : 0;
        __syncthreads();
        lds[t] += x;
        __syncthreads();
    }
    int incl = lds[t];
    int run = incl - s;   // exclusive across threads
#pragma unroll
    for (int k = 0; k < 4; k++) {
        if (base + k < n) rsp[base + k] = run;
        run += v[k];
    }
    if (t == 255) bsum[b] = incl;
}

__global__ __launch_bounds__(256) void scan2_kernel(int* __restrict__ bsum, int nb) {
    __shared__ int lds[256];
    int t = threadIdx.x;
    int s = (t < nb) ? bsum[t] : 0;
    lds[t] = s;
    __syncthreads();
    for (int off = 1; off < 256; off <<= 1) {
        int x = (t >= off) ? lds[t - off] : 0;
        __syncthreads();
        lds[t] += x;
        __syncthreads();
    }
    if (t < nb) bsum[t] = lds[t] - s;   // exclusive
}

__global__ void scan3_kernel(int* __restrict__ rsp, int* __restrict__ cursor,
                             const int* __restrict__ bsum,
                             const int* __restrict__ cnt,
                             ushort* __restrict__ esrc, int n) {
    int i = blockIdx.x * blockDim.x + threadIdx.x;
    if (i >= n) return;
    int v = rsp[i] + bsum[i >> 10];   // >>10 == /SCAN_IPB
    rsp[i] = v;
    cursor[i] = v + 1;                // slot v holds the self-edge
    esrc[v] = (ushort)i;              // self-loop as a real edge
    int ci = cnt[i];
    int pc = (ci + 8) & ~7;
    for (int p = v + 1 + ci; p < v + pc; p++) esrc[p] = (ushort)n;  // pads
    if (i == n - 1) rsp[n] = v + pc;
}

// ---------------------------------------------------------------- CSR fill
// Partition-local: each partition reads ONLY its own 0.4MB bucket; cursor
// atomics land on its 25KB slice.
__global__ __launch_bounds__(256) void fill_kernel(
    const unsigned* __restrict__ ebuf, const int* __restrict__ pcnt,
    int* __restrict__ cursor, ushort* __restrict__ esrc) {
    int part = blockIdx.x & 7;
    int m = min(pcnt[part], ECAP);
    const unsigned* bk = ebuf + (size_t)part * ECAP;
    int stride = (int)(gridDim.x >> 3) * 256;
    for (int e = (int)(blockIdx.x >> 3) * 256 + threadIdx.x; e < m; e += stride) {
        unsigned pe = bk[e];
        int d = pe >> 16;
        int s = pe & 0xffff;
        int p = atomicAdd(&cursor[d], 1);
        esrc[p] = (ushort)s;
    }
}

// ---------------------------------------------------------------- MFMA GEMM v3
// C = relu?(A) @ W, bf16 hi/lo split. Wave = 64 rows x 4 N-tiles: per k0,
// 4 A-frags (hi/lo) loaded once, each B hi/lo pair feeds 12 MFMAs.
// C chunk-major with pitch (n_rows+1), rows PRE-SCALED by dis[row].
template <bool RELU_IN>
__global__ __launch_bounds__(256, 2) void gemm_mfma(
    const float* __restrict__ A, const ushort* __restrict__ Bthi,
    const ushort* __restrict__ Btlo, const float* __restrict__ dis,
    float* __restrict__ C, int n_rows) {
    const int tid = threadIdx.x;
    const int bm0 = blockIdx.x * 256;        // block covers 256 rows
    const int wv = tid >> 6;
    const int lane = tid & 63;
    const int col = lane & 15;     // A row-in-frag / B col / C col
    const int quad = lane >> 4;    // k-block for A/B; row-quad for C
    const int rbase = bm0 + wv * 64 + col;   // wave rows: rbase + m*16
    const int ntBase = blockIdx.y * 4;

    f32x4 acc[4][4];   // [m][nt]
#pragma unroll
    for (int m = 0; m < 4; m++)
#pragma unroll
        for (int t = 0; t < 4; t++) acc[m][t] = (f32x4){0.f, 0.f, 0.f, 0.f};

#pragma unroll
    for (int k0 = 0; k0 < 4; k0++) {
        const int kb = k0 * 32 + quad * 8;
        bf16x8 ah[4], al[4];
#pragma unroll
        for (int m = 0; m < 4; m++) {
            int arow = rbase + m * 16;
            bool av = (arow < n_rows);
            const float* __restrict__ Ap = A + (size_t)arow * CH + kb;
            float4 f0 = av ? *(const float4*)Ap       : make_float4(0.f, 0.f, 0.f, 0.f);
            float4 f1 = av ? *(const float4*)(Ap + 4) : make_float4(0.f, 0.f, 0.f, 0.f);
            if (RELU_IN) {
                f0.x = fmaxf(f0.x, 0.f); f0.y = fmaxf(f0.y, 0.f);
                f0.z = fmaxf(f0.z, 0.f); f0.w = fmaxf(f0.w, 0.f);
                f1.x = fmaxf(f1.x, 0.f); f1.y = fmaxf(f1.y, 0.f);
                f1.z = fmaxf(f1.z, 0.f); f1.w = fmaxf(f1.w, 0.f);
            }
            float fa[8] = {f0.x, f0.y, f0.z, f0.w, f1.x, f1.y, f1.z, f1.w};
#pragma unroll
            for (int j = 0; j < 8; j++) {
                ushort h = f2bf(fa[j]);
                ah[m][j] = (short)h;
                al[m][j] = (short)f2bf(fa[j] - bf2f(h));
            }
        }
#pragma unroll
        for (int t = 0; t < 4; t++) {
            const int boff = ((ntBase + t) * 16 + col) * CH + kb;
            bf16x8 bh = *(const bf16x8*)&Bthi[boff];
            bf16x8 bl = *(const bf16x8*)&Btlo[boff];
#pragma unroll
            for (int m = 0; m < 4; m++) {
                acc[m][t] = __builtin_amdgcn_mfma_f32_16x16x32_bf16(ah[m], bh, acc[m][t], 0, 0, 0);
                acc[m][t] = __builtin_amdgcn_mfma_f32_16x16x32_bf16(ah[m], bl, acc[m][t], 0, 0, 0);
                acc[m][t] = __builtin_amdgcn_mfma_f32_16x16x32_bf16(al[m], bh, acc[m][t], 0, 0, 0);
            }
        }
    }

    // epilogue: C/D layout col=lane&15, row=quad*4+reg (m89-verified)
#pragma unroll
    for (int m = 0; m < 4; m++) {
#pragma unroll
        for (int reg = 0; reg < 4; reg++) {
            int gr = bm0 + wv * 64 + m * 16 + quad * 4 + reg;
            if (gr < n_rows) {
                float d = dis[gr];
#pragma unroll
                for (int t = 0; t < 4; t++) {
                    int nt = ntBase + t;
                    C[((size_t)nt * (n_rows + 1) + gr) * CHK + col] = acc[m][t][reg] * d;
                }
            }
        }
    }
}

// ---------------------------------------------------------------- CSR gather
// wave = (16 nodes, 1 chunk); chunk = blockIdx%8 pins the 3.2MB slice/XCD.
// (a) each block linearly pre-warms its share of the chunk slice -- converts
// the random-order first-touch into sequential fetch; (b) out-stores are
// NON-TEMPORAL so the write stream doesn't evict the slice. esrc loads are
// plain cached loads (nt on them was a 50% regression, R2). Dense CSR keeps
// the per-XCD esrc stream at 2.4MB (vs 6.4MB fixed-stride, R1).
__global__ __launch_bounds__(256) void gather_kernel(
    const int* __restrict__ rsp, const ushort* __restrict__ esrc,
    const float* __restrict__ dis, const float* __restrict__ hC,
    const float* __restrict__ bias, float* __restrict__ out, int n) {
    int c = blockIdx.x & 7;
    int wv = threadIdx.x >> 6;
    int lane = threadIdx.x & 63;
    int g = lane >> 2;    // node slot 0..15
    int q = lane & 3;     // float4 within the 16-channel row
    int i = (blockIdx.x >> 3) * 64 + wv * 16 + g;
    bool valid = (i < n);
    int iw = valid ? i : 0;
    const float4* __restrict__ h4 = (const float4*)(hC + (size_t)c * (n + 1) * CHK);

    // sequential L2 pre-warm: one float4 per thread covers the slice
    float warm = 0.f;
    {
        int nblk = (n + 63) >> 6;                       // blocks per chunk
        size_t p = (size_t)(blockIdx.x >> 3) * 256 + threadIdx.x;
        size_t sliceF4 = ((size_t)(n + 1) * CHK) >> 2;  // float4 count
        for (; p < sliceF4; p += (size_t)nblk * 256) {
            float4 v = h4[p];
            warm += v.x + v.y + v.z + v.w;
        }
    }

    int beg = valid ? rsp[iw] : 0;
    int end = valid ? rsp[iw + 1] : 0;
    float4 acc = make_float4(0.f, 0.f, 0.f, 0.f);
    for (int j = beg; j < end; j += 8) {   // beg/end are multiples of 8
        ushort4 e0 = *(const ushort4*)&esrc[j];
        ushort4 e1 = *(const ushort4*)&esrc[j + 4];
        float4 v0 = h4[(size_t)e0.x * 4 + q];
        float4 v1 = h4[(size_t)e0.y * 4 + q];
        float4 v2 = h4[(size_t)e0.z * 4 + q];
        float4 v3 = h4[(size_t)e0.w * 4 + q];
        float4 v4 = h4[(size_t)e1.x * 4 + q];
        float4 v5 = h4[(size_t)e1.y * 4 + q];
        float4 v6 = h4[(size_t)e1.z * 4 + q];
        float4 v7 = h4[(size_t)e1.w * 4 + q];
        acc.x += v0.x; acc.y += v0.y; acc.z += v0.z; acc.w += v0.w;
        acc.x += v1.x; acc.y += v1.y; acc.z += v1.z; acc.w += v1.w;
        acc.x += v2.x; acc.y += v2.y; acc.z += v2.z; acc.w += v2.w;
        acc.x += v3.x; acc.y += v3.y; acc.z += v3.z; acc.w += v3.w;
        acc.x += v4.x; acc.y += v4.y; acc.z += v4.z; acc.w += v4.w;
        acc.x += v5.x; acc.y += v5.y; acc.z += v5.z; acc.w += v5.w;
        acc.x += v6.x; acc.y += v6.y; acc.z += v6.z; acc.w += v6.w;
        acc.x += v7.x; acc.y += v7.y; acc.z += v7.z; acc.w += v7.w;
    }
    // keep the warm loads alive (cannot be DCE'd)
    __asm__ volatile("" : : "v"(warm));
    if (valid) {
        float di = dis[iw];
        float4 bv = ((const float4*)bias)[c * 4 + q];
        f32x4 o;
        o[0] = bv.x + di * acc.x;
        o[1] = bv.y + di * acc.y;
        o[2] = bv.z + di * acc.z;
        o[3] = bv.w + di * acc.w;
        __builtin_nontemporal_store(o, (f32x4*)&((float4*)out)[(size_t)iw * 32 + c * 4 + q]);
    }
}

// ---------------------------------------------------------------- head
__global__ __launch_bounds__(256) void head_kernel(
    const float* __restrict__ A, const float* __restrict__ Wh,
    const float* __restrict__ bh, float* __restrict__ out, int n) {
    __shared__ float Ws[CH * NCLS];
    __shared__ float As[16][129];
    const int tid = threadIdx.x;
    const int n0 = blockIdx.x * 16;
#pragma unroll
    for (int i = 0; i < 8; i++) {
        int l = tid + i * 256;
        Ws[l] = Wh[l];
    }
#pragma unroll
    for (int i = 0; i < 8; i++) {
        int l = tid + i * 256;
        int r = l >> 7, c = l & 127;
        int gr = n0 + r;
        As[r][c] = (gr < n) ? fmaxf(A[(size_t)gr * CH + c], 0.0f) : 0.0f;
    }
    __syncthreads();
    int r = tid >> 4, c = tid & 15;
    float acc = bh[c];
#pragma unroll
    for (int k = 0; k < CH; k++) acc = fmaf(As[r][k], Ws[k * NCLS + c], acc);
    int gr = n0 + r;
    if (gr < n) out[(size_t)gr * NCLS + c] = acc;
}

// ---------------------------------------------------------------- launch
extern "C" void kernel_launch(void* const* d_in, const int* in_sizes, int n_in,
                              void* d_out, int out_size, void* d_ws, size_t ws_size,
                              hipStream_t stream) {
    const float* x  = (const float*)d_in[0];
    const int*   ei = (const int*)d_in[1];
    const float* W1 = (const float*)d_in[2];
    const float* b1 = (const float*)d_in[3];
    const float* W2 = (const float*)d_in[4];
    const float* b2 = (const float*)d_in[5];
    const float* Wh = (const float*)d_in[6];
    const float* bh = (const float*)d_in[7];
    float* out = (float*)d_out;

    const int n = in_sizes[0] / CH;   // 50000
    const int E = in_sizes[1] / 2;    // 800000
    const int* src = ei;
    const int* dst = ei + E;

    // workspace layout (all chunks 16B aligned)
    ushort* w1hi = (ushort*)d_ws;                    // 16384 each
    ushort* w1lo = w1hi + CH * CH;
    ushort* w2hi = w1lo + CH * CH;
    ushort* w2lo = w2hi + CH * CH;
    float* dis  = (float*)(w2lo + CH * CH);          // n
    float* bufA = dis + n;                           // (n+1)*128 chunk-major h'
    float* bufB = bufA + (size_t)(n + 1) * CH;       // n*128 row-major
    int* cnt    = (int*)(bufB + (size_t)n * CH);     // n
    int* rsp    = cnt + n;                           // n+1 (padded CSR starts)
    int* cursor = rsp + n + 1;                       // n
    int* bsum   = cursor + n;                        // up to 256
    int* pcnt   = bsum + 256;                        // 8
    ushort* esrc = (ushort*)(pcnt + 8);              // <= E + 8n padded edges
    unsigned* ebuf = (unsigned*)bufB;                // 8*ECAP = 4MB, aliases
                                                     // bufB (dead till gather1)

    const int B = 256;
    const int nb_scan = (n + SCAN_IPB - 1) / SCAN_IPB;   // 49
    const int nbz = (n + B - 1) / B;                     // cnt-zero blocks
    const float p8n = 8.0f / (float)n;                   // partition map scale

    // ---- prep + bucketed dense-CSR build
    prep_kernel<<<128 + nbz + 1, B, 0, stream>>>(W1, W2, w1hi, w1lo, w2hi, w2lo,
                                                 cnt, pcnt, bufA, n, nbz);
    bucket_kernel<<<(E + 1023) / 1024, B, 0, stream>>>(src, dst, ebuf, pcnt, E, p8n);
    count_kernel<<<2048, B, 0, stream>>>(ebuf, pcnt, cnt);
    scan1_kernel<<<nb_scan, B, 0, stream>>>(cnt, rsp, bsum, dis, n);
    scan2_kernel<<<1, B, 0, stream>>>(bsum, nb_scan);
    scan3_kernel<<<(n + B - 1) / B, B, 0, stream>>>(rsp, cursor, bsum, cnt, esrc, n);
    fill_kernel<<<2048, B, 0, stream>>>(ebuf, pcnt, cursor, esrc);

    const dim3 gemmGrid((n + 255) / 256, 2);
    const int gatherGrid = NCHUNK * ((n + 63) / 64);   // 64 nodes/block/chunk

    // layer 1
    gemm_mfma<false><<<gemmGrid, B, 0, stream>>>(x, w1hi, w1lo, dis, bufA, n);
    gather_kernel<<<gatherGrid, B, 0, stream>>>(rsp, esrc, dis, bufA, b1, bufB, n);
    // layer 2
    gemm_mfma<true><<<gemmGrid, B, 0, stream>>>(bufB, w2hi, w2lo, dis, bufA, n);
    gather_kernel<<<gatherGrid, B, 0, stream>>>(rsp, esrc, dis, bufA, b2, bufB, n);
    // head
    head_kernel<<<(n + 15) / 16, B, 0, stream>>>(bufB, Wh, bh, out, n);
}

// Round 4
// 296.221 us; speedup vs baseline: 1.1752x; 1.0854x over previous
//
#include <hip/hip_runtime.h>

#define CH 128
#define NCLS 16
#define CHK 16          // channels per chunk
#define NCHUNK 8        // 8 chunks of 16 == 128 channels, one per XCD
#define ECAP 131072     // bucket capacity per partition (E/8 = 100k expected)

typedef __attribute__((ext_vector_type(8))) short bf16x8;
typedef __attribute__((ext_vector_type(4))) float f32x4;

__device__ inline ushort f2bf(float f) {        // RTNE fp32 -> bf16 bits
    unsigned u = __float_as_uint(f);
    unsigned r = u + 0x7fffu + ((u >> 16) & 1u);
    return (ushort)(r >> 16);
}
__device__ inline float bf2f(ushort b) {
    return __uint_as_float(((unsigned)b) << 16);
}

// ---------------------------------------------------------------- prep (fused)
// b<128: bf16 hi/lo weight split. Next nbz blocks: zero cnt. Last block:
// zero bufA row n per chunk + pcnt + galloc.
__global__ __launch_bounds__(256) void prep_kernel(
    const float* __restrict__ W1, const float* __restrict__ W2,
    ushort* __restrict__ w1hi, ushort* __restrict__ w1lo,
    ushort* __restrict__ w2hi, ushort* __restrict__ w2lo,
    int* __restrict__ cnt, int* __restrict__ pcnt, int* __restrict__ galloc,
    float* __restrict__ bufA, int n, int nbz) {
    int b = blockIdx.x, tid = threadIdx.x;
    if (b < 128) {
        const float* W = (b < 64) ? W1 : W2;
        ushort* Whi = (b < 64) ? w1hi : w2hi;
        ushort* Wlo = (b < 64) ? w1lo : w2lo;
        int t = ((b & 63) << 8) + tid;
        int k = t >> 7, nn = t & 127;
        float v = W[t];
        ushort h = f2bf(v);
        Whi[nn * CH + k] = h;
        Wlo[nn * CH + k] = f2bf(v - bf2f(h));
    } else if (b < 128 + nbz) {
        int i = (b - 128) * 256 + tid;
        if (i < n) cnt[i] = 0;
    } else {
        if (tid < NCHUNK * CHK) {
            int c = tid >> 4, ch = tid & 15;
            bufA[((size_t)c * (n + 1) + n) * CHK + ch] = 0.0f;
        }
        if (tid < 8) pcnt[tid] = 0;
        if (tid == 8) *galloc = 0;
    }
}

// ------------------------------------------------------- bucket + count pass
// ONE pass over edges: pack (dst<<16)|src into 8 dst-partition buckets AND
// count degrees (fused -- no separate count kernel / edge re-read).
__global__ __launch_bounds__(256) void bucketcount_kernel(
    const int* __restrict__ src, const int* __restrict__ dst,
    unsigned* __restrict__ ebuf, int* __restrict__ pcnt,
    int* __restrict__ cnt, int E, float p8n) {
    __shared__ int lpos[8];
    __shared__ int lbase[8];
    int tid = threadIdx.x;
    if (tid < 8) lpos[tid] = 0;
    __syncthreads();
    int i0 = (blockIdx.x * 256 + tid) * 4;
    int part[4]; int off[4]; unsigned pk[4]; int c = 0;
    if (i0 + 3 < E) {
        int4 s4 = *(const int4*)&src[i0];
        int4 d4 = *(const int4*)&dst[i0];
        int ss[4] = {s4.x, s4.y, s4.z, s4.w};
        int dd[4] = {d4.x, d4.y, d4.z, d4.w};
        c = 4;
#pragma unroll
        for (int k = 0; k < 4; k++) {
            part[k] = min(7, (int)((float)dd[k] * p8n));
            pk[k] = ((unsigned)dd[k] << 16) | (unsigned)ss[k];
            off[k] = atomicAdd(&lpos[part[k]], 1);
            atomicAdd(&cnt[dd[k]], 1);
        }
    } else {
        for (int k = 0; k < 4 && i0 + k < E; k++) {
            int s = src[i0 + k], d = dst[i0 + k];
            part[c] = min(7, (int)((float)d * p8n));
            pk[c] = ((unsigned)d << 16) | (unsigned)s;
            off[c] = atomicAdd(&lpos[part[c]], 1);
            atomicAdd(&cnt[d], 1);
            c++;
        }
    }
    __syncthreads();
    if (tid < 8) lbase[tid] = atomicAdd(&pcnt[tid], lpos[tid]);
    __syncthreads();
    for (int k = 0; k < c; k++) {
        int idx = lbase[part[k]] + off[k];
        if (idx < ECAP) ebuf[(size_t)part[k] * ECAP + idx] = pk[k];
    }
}

// ---------------------------------------------------------------- place
// Dense-CSR region allocator, NO global scan: block-local LDS scan of
// round8(deg+1) + ONE global atomicAdd per block. Regions unordered across
// blocks (fine -- gather locates via rsp[i]). Writes self-edge + pads.
// All sizes are multiples of 8 -> every region base is 8-aligned.
__global__ __launch_bounds__(256) void place_kernel(
    const int* __restrict__ cnt, int* __restrict__ rsp,
    int* __restrict__ cursor, int* __restrict__ galloc,
    ushort* __restrict__ esrc, int n) {
    __shared__ int lds[256];
    __shared__ int gbase;
    int t = threadIdx.x;
    int i = blockIdx.x * 256 + t;
    int c = (i < n) ? cnt[i] : 0;
    int sz = (i < n) ? ((c + 8) & ~7) : 0;   // round8(deg+1)
    lds[t] = sz;
    __syncthreads();
    for (int off = 1; off < 256; off <<= 1) {
        int x = (t >= off) ? lds[t - off] : 0;
        __syncthreads();
        lds[t] += x;
        __syncthreads();
    }
    int incl = lds[t];
    if (t == 255) gbase = atomicAdd(galloc, incl);
    __syncthreads();
    int base = gbase + incl - sz;
    if (i < n) {
        rsp[i] = base;
        cursor[i] = base + 1;          // slot base holds the self-edge
        esrc[base] = (ushort)i;
        for (int p = base + 1 + c; p < base + sz; p++) esrc[p] = (ushort)n;
    }
}

// ---------------------------------------------------------------- GEMM body
// C = relu?(A) @ W, bf16 hi/lo split. Wave = 64 rows x 4 N-tiles: per k0,
// 4 A-frags (hi/lo) loaded once, each B hi/lo pair feeds 12 MFMAs.
// C chunk-major with pitch (n_rows+1), rows PRE-SCALED by rsqrt(cnt[row]+1).
template <bool RELU_IN>
__device__ __forceinline__ void gemm_body(
    int bx, int by, const float* __restrict__ A,
    const ushort* __restrict__ Bthi, const ushort* __restrict__ Btlo,
    const int* __restrict__ cntp, float* __restrict__ C, int n_rows) {
    const int tid = threadIdx.x;
    const int bm0 = bx * 256;                // block covers 256 rows
    const int wv = tid >> 6;
    const int lane = tid & 63;
    const int col = lane & 15;     // A row-in-frag / B col / C col
    const int quad = lane >> 4;    // k-block for A/B; row-quad for C
    const int rbase = bm0 + wv * 64 + col;   // wave rows: rbase + m*16
    const int ntBase = by * 4;

    f32x4 acc[4][4];   // [m][nt]
#pragma unroll
    for (int m = 0; m < 4; m++)
#pragma unroll
        for (int t = 0; t < 4; t++) acc[m][t] = (f32x4){0.f, 0.f, 0.f, 0.f};

#pragma unroll
    for (int k0 = 0; k0 < 4; k0++) {
        const int kb = k0 * 32 + quad * 8;
        bf16x8 ah[4], al[4];
#pragma unroll
        for (int m = 0; m < 4; m++) {
            int arow = rbase + m * 16;
            bool av = (arow < n_rows);
            const float* __restrict__ Ap = A + (size_t)arow * CH + kb;
            float4 f0 = av ? *(const float4*)Ap       : make_float4(0.f, 0.f, 0.f, 0.f);
            float4 f1 = av ? *(const float4*)(Ap + 4) : make_float4(0.f, 0.f, 0.f, 0.f);
            if (RELU_IN) {
                f0.x = fmaxf(f0.x, 0.f); f0.y = fmaxf(f0.y, 0.f);
                f0.z = fmaxf(f0.z, 0.f); f0.w = fmaxf(f0.w, 0.f);
                f1.x = fmaxf(f1.x, 0.f); f1.y = fmaxf(f1.y, 0.f);
                f1.z = fmaxf(f1.z, 0.f); f1.w = fmaxf(f1.w, 0.f);
            }
            float fa[8] = {f0.x, f0.y, f0.z, f0.w, f1.x, f1.y, f1.z, f1.w};
#pragma unroll
            for (int j = 0; j < 8; j++) {
                ushort h = f2bf(fa[j]);
                ah[m][j] = (short)h;
                al[m][j] = (short)f2bf(fa[j] - bf2f(h));
            }
        }
#pragma unroll
        for (int t = 0; t < 4; t++) {
            const int boff = ((ntBase + t) * 16 + col) * CH + kb;
            bf16x8 bh = *(const bf16x8*)&Bthi[boff];
            bf16x8 bl = *(const bf16x8*)&Btlo[boff];
#pragma unroll
            for (int m = 0; m < 4; m++) {
                acc[m][t] = __builtin_amdgcn_mfma_f32_16x16x32_bf16(ah[m], bh, acc[m][t], 0, 0, 0);
                acc[m][t] = __builtin_amdgcn_mfma_f32_16x16x32_bf16(ah[m], bl, acc[m][t], 0, 0, 0);
                acc[m][t] = __builtin_amdgcn_mfma_f32_16x16x32_bf16(al[m], bh, acc[m][t], 0, 0, 0);
            }
        }
    }

    // epilogue: C/D layout col=lane&15, row=quad*4+reg (m89-verified)
#pragma unroll
    for (int m = 0; m < 4; m++) {
#pragma unroll
        for (int reg = 0; reg < 4; reg++) {
            int gr = bm0 + wv * 64 + m * 16 + quad * 4 + reg;
            if (gr < n_rows) {
                float d = rsqrtf((float)cntp[gr] + 1.0f);
#pragma unroll
                for (int t = 0; t < 4; t++) {
                    int nt = ntBase + t;
                    C[((size_t)nt * (n_rows + 1) + gr) * CHK + col] = acc[m][t][reg] * d;
                }
            }
        }
    }
}

// ------------------------------------------------- fused GEMM || CSR-fill
// Blocks [0, gemmBlocks): the MFMA GEMM. Blocks [gemmBlocks, +2048): the
// bucket-fed CSR fill (independent work: fill touches esrc/cursor, gemm
// reads x/weights/cnt and writes bufA). gemm blocks dispatch first (long
// pole); fill blocks backfill remaining CU slots and hide under the GEMM.
template <bool RELU_IN>
__global__ __launch_bounds__(256, 2) void gemmfill_kernel(
    const float* __restrict__ A, const ushort* __restrict__ Bthi,
    const ushort* __restrict__ Btlo, const int* __restrict__ cntp,
    float* __restrict__ C, int n_rows, int nbx, int gemmBlocks,
    const unsigned* __restrict__ ebuf, const int* __restrict__ pcnt,
    int* __restrict__ cursor, ushort* __restrict__ esrc) {
    int b = blockIdx.x;
    if (b < gemmBlocks) {
        gemm_body<RELU_IN>(b % nbx, b / nbx, A, Bthi, Btlo, cntp, C, n_rows);
    } else {
        int fb = b - gemmBlocks;              // 0..2047
        int part = fb & 7;
        int m = min(pcnt[part], ECAP);
        const unsigned* bk = ebuf + (size_t)part * ECAP;
        for (int e = (fb >> 3) * 256 + (int)threadIdx.x; e < m; e += 256 * 256) {
            unsigned pe = bk[e];
            int p = atomicAdd(&cursor[pe >> 16], 1);
            esrc[p] = (ushort)(pe & 0xffffu);
        }
    }
}

// ---------------------------------------------------------------- CSR gather
// wave = (16 nodes, 1 chunk); chunk = blockIdx%8 pins the 3.2MB slice/XCD.
// (a) each block linearly pre-warms its share of the chunk slice; (b) out-
// stores NON-TEMPORAL; (c) esrc plain cached (nt was a 50% regression, R2);
// dense CSR keeps the per-XCD esrc stream at 2.4MB. Node i's edges at
// [rsp[i], rsp[i]+round8(cnt[i]+1)); dst scale rsqrt(cnt+1) computed here.
__global__ __launch_bounds__(256) void gather_kernel(
    const int* __restrict__ rsp, const int* __restrict__ cnt,
    const ushort* __restrict__ esrc, const float* __restrict__ hC,
    const float* __restrict__ bias, float* __restrict__ out, int n) {
    int c = blockIdx.x & 7;
    int wv = threadIdx.x >> 6;
    int lane = threadIdx.x & 63;
    int g = lane >> 2;    // node slot 0..15
    int q = lane & 3;     // float4 within the 16-channel row
    int i = (blockIdx.x >> 3) * 64 + wv * 16 + g;
    bool valid = (i < n);
    int iw = valid ? i : 0;
    const float4* __restrict__ h4 = (const float4*)(hC + (size_t)c * (n + 1) * CHK);

    // sequential L2 pre-warm: one float4 per thread covers the slice
    float warm = 0.f;
    {
        int nblk = (n + 63) >> 6;                       // blocks per chunk
        size_t p = (size_t)(blockIdx.x >> 3) * 256 + threadIdx.x;
        size_t sliceF4 = ((size_t)(n + 1) * CHK) >> 2;  // float4 count
        for (; p < sliceF4; p += (size_t)nblk * 256) {
            float4 v = h4[p];
            warm += v.x + v.y + v.z + v.w;
        }
    }

    int beg = valid ? rsp[iw] : 0;
    int cv  = valid ? cnt[iw] : -8;
    int pc  = (cv + 8) & ~7;          // round8(deg+1); 0 for invalid
    float4 acc = make_float4(0.f, 0.f, 0.f, 0.f);
    for (int j = beg; j < beg + pc; j += 8) {   // beg is a multiple of 8
        ushort4 e0 = *(const ushort4*)&esrc[j];
        ushort4 e1 = *(const ushort4*)&esrc[j + 4];
        float4 v0 = h4[(size_t)e0.x * 4 + q];
        float4 v1 = h4[(size_t)e0.y * 4 + q];
        float4 v2 = h4[(size_t)e0.z * 4 + q];
        float4 v3 = h4[(size_t)e0.w * 4 + q];
        float4 v4 = h4[(size_t)e1.x * 4 + q];
        float4 v5 = h4[(size_t)e1.y * 4 + q];
        float4 v6 = h4[(size_t)e1.z * 4 + q];
        float4 v7 = h4[(size_t)e1.w * 4 + q];
        acc.x += v0.x; acc.y += v0.y; acc.z += v0.z; acc.w += v0.w;
        acc.x += v1.x; acc.y += v1.y; acc.z += v1.z; acc.w += v1.w;
        acc.x += v2.x; acc.y += v2.y; acc.z += v2.z; acc.w += v2.w;
        acc.x += v3.x; acc.y += v3.y; acc.z += v3.z; acc.w += v3.w;
        acc.x += v4.x; acc.y += v4.y; acc.z += v4.z; acc.w += v4.w;
        acc.x += v5.x; acc.y += v5.y; acc.z += v5.z; acc.w += v5.w;
        acc.x += v6.x; acc.y += v6.y; acc.z += v6.z; acc.w += v6.w;
        acc.x += v7.x; acc.y += v7.y; acc.z += v7.z; acc.w += v7.w;
    }
    // keep the warm loads alive (cannot be DCE'd)
    __asm__ volatile("" : : "v"(warm));
    if (valid) {
        float di = rsqrtf((float)cv + 1.0f);
        float4 bv = ((const float4*)bias)[c * 4 + q];
        f32x4 o;
        o[0] = bv.x + di * acc.x;
        o[1] = bv.y + di * acc.y;
        o[2] = bv.z + di * acc.z;
        o[3] = bv.w + di * acc.w;
        __builtin_nontemporal_store(o, (f32x4*)&((float4*)out)[(size_t)iw * 32 + c * 4 + q]);
    }
}

// ---------------------------------------------------------------- head
__global__ __launch_bounds__(256) void head_kernel(
    const float* __restrict__ A, const float* __restrict__ Wh,
    const float* __restrict__ bh, float* __restrict__ out, int n) {
    __shared__ float Ws[CH * NCLS];
    __shared__ float As[16][129];
    const int tid = threadIdx.x;
    const int n0 = blockIdx.x * 16;
#pragma unroll
    for (int i = 0; i < 8; i++) {
        int l = tid + i * 256;
        Ws[l] = Wh[l];
    }
#pragma unroll
    for (int i = 0; i < 8; i++) {
        int l = tid + i * 256;
        int r = l >> 7, c = l & 127;
        int gr = n0 + r;
        As[r][c] = (gr < n) ? fmaxf(A[(size_t)gr * CH + c], 0.0f) : 0.0f;
    }
    __syncthreads();
    int r = tid >> 4, c = tid & 15;
    float acc = bh[c];
#pragma unroll
    for (int k = 0; k < CH; k++) acc = fmaf(As[r][k], Ws[k * NCLS + c], acc);
    int gr = n0 + r;
    if (gr < n) out[(size_t)gr * NCLS + c] = acc;
}

// ---------------------------------------------------------------- launch
extern "C" void kernel_launch(void* const* d_in, const int* in_sizes, int n_in,
                              void* d_out, int out_size, void* d_ws, size_t ws_size,
                              hipStream_t stream) {
    const float* x  = (const float*)d_in[0];
    const int*   ei = (const int*)d_in[1];
    const float* W1 = (const float*)d_in[2];
    const float* b1 = (const float*)d_in[3];
    const float* W2 = (const float*)d_in[4];
    const float* b2 = (const float*)d_in[5];
    const float* Wh = (const float*)d_in[6];
    const float* bh = (const float*)d_in[7];
    float* out = (float*)d_out;

    const int n = in_sizes[0] / CH;   // 50000
    const int E = in_sizes[1] / 2;    // 800000
    const int* src = ei;
    const int* dst = ei + E;

    // workspace layout (all chunks 16B aligned)
    ushort* w1hi = (ushort*)d_ws;                    // 16384 each
    ushort* w1lo = w1hi + CH * CH;
    ushort* w2hi = w1lo + CH * CH;
    ushort* w2lo = w2hi + CH * CH;
    float* bufA = (float*)(w2lo + CH * CH);          // (n+1)*128 chunk-major h'
    float* bufB = bufA + (size_t)(n + 1) * CH;       // n*128 row-major
    int* cnt    = (int*)(bufB + (size_t)n * CH);     // n  (in-degrees)
    int* rsp    = cnt + n;                           // n  (region starts)
    int* cursor = rsp + n;                           // n
    int* pcnt   = cursor + n;                        // 8
    int* galloc = pcnt + 8;                          // 1 (+7 pad)
    ushort* esrc = (ushort*)(pcnt + 16);             // <= E + 8n padded edges
    unsigned* ebuf = (unsigned*)bufB;                // 8*ECAP = 4MB, aliases
                                                     // bufB (dead till gather1)

    const int B = 256;
    const int nbz = (n + B - 1) / B;                 // cnt-zero / place blocks
    const int nbx = (n + 255) / 256;                 // gemm x-blocks (196)
    const int gemmBlocks = nbx * 2;                  // 392
    const float p8n = 8.0f / (float)n;               // partition map scale

    // ---- build: bucket+count (1 edge pass) -> place (block allocator)
    prep_kernel<<<128 + nbz + 1, B, 0, stream>>>(W1, W2, w1hi, w1lo, w2hi, w2lo,
                                                 cnt, pcnt, galloc, bufA, n, nbz);
    bucketcount_kernel<<<(E + 1023) / 1024, B, 0, stream>>>(src, dst, ebuf, pcnt,
                                                            cnt, E, p8n);
    place_kernel<<<nbz, B, 0, stream>>>(cnt, rsp, cursor, galloc, esrc, n);

    const int gatherGrid = NCHUNK * ((n + 63) / 64);   // 64 nodes/block/chunk

    // layer 1 (gemm || csr-fill fused; fill hides under the GEMM)
    gemmfill_kernel<false><<<gemmBlocks + 2048, B, 0, stream>>>(
        x, w1hi, w1lo, cnt, bufA, n, nbx, gemmBlocks, ebuf, pcnt, cursor, esrc);
    gather_kernel<<<gatherGrid, B, 0, stream>>>(rsp, cnt, esrc, bufA, b1, bufB, n);
    // layer 2
    gemmfill_kernel<true><<<gemmBlocks, B, 0, stream>>>(
        bufB, w2hi, w2lo, cnt, bufA, n, nbx, gemmBlocks, ebuf, pcnt, cursor, esrc);
    gather_kernel<<<gatherGrid, B, 0, stream>>>(rsp, cnt, esrc, bufA, b2, bufB, n);
    // head
    head_kernel<<<(n + 15) / 16, B, 0, stream>>>(bufB, Wh, bh, out, n);
}